// Round 10
// baseline (280.091 us; speedup 1.0000x reference)
//
#include <hip/hip_runtime.h>
#include <hip/hip_bf16.h>
#include <stdint.h>

// GeometricGNN on MI355X. R=2048, APR=8, H=512, HEADS=4, HD=128, SD=28.
// Round 27: R26 with attention at 16 waves/block (1024 thr), grid (64,4)
// = 256 blocks (1/CU). Main loop now 4 waves/SIMD (was 2). Each wave does
// 4 kt-iterations (kt = w, w+16, ...). Per-wave body identical to attn3b
// (staged K + Ash alias + reg V). Reduction extended to 16 waves:
// Ored [16][32][68] + dred [16][32][4] = 147456 B static LDS.
// Everything else R26/R23 verbatim.

#define R_ 2048
#define APR_ 8
#define H_ 512
#define HEADS_ 4
#define HD_ 128
#define FA_LD 544

typedef __attribute__((ext_vector_type(4))) float f32x4;
typedef __attribute__((ext_vector_type(4))) unsigned int u32x4;
typedef __attribute__((ext_vector_type(4))) unsigned short us4;
typedef __bf16 bf16x8 __attribute__((ext_vector_type(8)));

static __device__ __forceinline__ float bf2f(unsigned short u) {
    union { unsigned int i; float f; } c; c.i = ((unsigned int)u) << 16; return c.f;
}
static __device__ __forceinline__ unsigned short f2bf(float f) {
    union { float f; unsigned int i; } c; c.f = f;
    unsigned int r = c.i + 0x7fffu + ((c.i >> 16) & 1u);   // RNE
    return (unsigned short)(r >> 16);
}
// flag-aware, sanitized load of logical element i of a float input array
static __device__ __forceinline__ float loadf(const void* p, size_t i, bool f32) {
    float v = f32 ? ((const float*)p)[i] : bf2f(((const unsigned short*)p)[i]);
    return (v == v && fabsf(v) < 1e30f) ? v : 0.f;
}

// ---------------------------------------------------------------- diag
__global__ void diag(unsigned short* out, float val) {
    if (threadIdx.x == 0 && blockIdx.x == 0) out[0] = f2bf(val);
}

// ---------------------------------------------------------------- dtype detect (d_in[0])
__global__ void detect_dtype(const unsigned short* __restrict__ nf, int* flag) {
    __shared__ int bad;
    if (threadIdx.x == 0) bad = 0;
    __syncthreads();
    int cnt = 0;
    for (int i = threadIdx.x; i < 8192; i += 256) {
        unsigned e = (nf[i] >> 7) & 0xFFu;
        if (e >= 0xC0u) cnt++;
    }
    atomicAdd(&bad, cnt);
    __syncthreads();
    if (threadIdx.x == 0) *flag = (bad > 16) ? 1 : 0;
}

// ---------------------------------------------------------------- gather + frames (+ca4)
__global__ void gather_frames(const void* __restrict__ pos,
                              const int* __restrict__ atype,
                              const int* __restrict__ flag,
                              int* __restrict__ cai, float* __restrict__ ca,
                              float* __restrict__ cb, float* __restrict__ fr,
                              float* __restrict__ maskf, f32x4* __restrict__ ca4)
{
    int r = blockIdx.x * blockDim.x + threadIdx.x;
    if (r >= R_) return;
    bool f32 = *flag != 0;
    int base = r * APR_;
    float caP[3] = {0,0,0}, cbP[3] = {0,0,0};
    int idx = base; bool h0=false, h1=false, h2=false;
    for (int a = 0; a < APR_; a++) {
        int t = atype[base + a];
        if (t == 0) h0 = true;
        if (t == 2) h2 = true;
        if (t == 1) { h1 = true; idx = base + a;
            for (int j = 0; j < 3; j++) caP[j] += loadf(pos, (size_t)(base+a)*3 + j, f32); }
        if (t == 4) {
            for (int j = 0; j < 3; j++) cbP[j] += loadf(pos, (size_t)(base+a)*3 + j, f32); }
    }
    float s = fabsf(cbP[0]) + fabsf(cbP[1]) + fabsf(cbP[2]);
    if (s < 1e-6f) { cbP[0]=caP[0]; cbP[1]=caP[1]; cbP[2]=caP[2]; }
    float e1[3] = { cbP[0]-caP[0], cbP[1]-caP[1], cbP[2]-caP[2] };
    float n1 = sqrtf(e1[0]*e1[0] + e1[1]*e1[1] + e1[2]*e1[2]);
    float e1u[3] = { e1[0], e1[1], e1[2] };
    if (n1 > 1e-6f) { float iv = 1.f / fmaxf(n1, 1e-6f); e1u[0]*=iv; e1u[1]*=iv; e1u[2]*=iv; }
    float e2a[3] = { e1u[1], -e1u[0], 0.f };
    float n2a = sqrtf(e2a[0]*e2a[0] + e2a[1]*e2a[1]);
    float e2b[3] = { -e1u[2], 0.f, e1u[0] };
    float n2b = sqrtf(e2b[0]*e2b[0] + e2b[2]*e2b[2]);
    bool useb = n2a < 1e-6f;
    float e2[3] = { useb?e2b[0]:e2a[0], useb?e2b[1]:e2a[1], useb?e2b[2]:e2a[2] };
    float n2 = useb ? n2b : n2a;
    float iv2 = 1.f / fmaxf(n2, 1e-6f);
    float e2u[3] = { e2[0]*iv2, e2[1]*iv2, e2[2]*iv2 };
    float e3[3] = { e1u[1]*e2u[2]-e1u[2]*e2u[1],
                    e1u[2]*e2u[0]-e1u[0]*e2u[2],
                    e1u[0]*e2u[1]-e1u[1]*e2u[0] };
    bool ok = (r < R_-1) && (n1 > 1e-6f) && (n2 > 1e-6f);
    float F[9];
    if (ok) { F[0]=e1u[0]; F[1]=e2u[0]; F[2]=e3[0];
              F[3]=e1u[1]; F[4]=e2u[1]; F[5]=e3[1];
              F[6]=e1u[2]; F[7]=e2u[2]; F[8]=e3[2]; }
    else    { F[0]=1;F[1]=0;F[2]=0; F[3]=0;F[4]=1;F[5]=0; F[6]=0;F[7]=0;F[8]=1; }
    cai[r] = idx;
    for (int j = 0; j < 3; j++) { ca[r*3+j] = caP[j]; cb[r*3+j] = cbP[j]; }
    for (int j = 0; j < 9; j++) fr[r*9+j] = F[j];
    float mk = (h0 && h1 && h2) ? 1.f : 0.f;
    maskf[r] = mk;
    f32x4 c4; c4[0]=caP[0]; c4[1]=caP[1]; c4[2]=caP[2]; c4[3]=mk;
    ca4[r] = c4;
}

// ---------------------------------------------------------------- pack_prep (R20 verbatim)
__global__ __launch_bounds__(256) void pack_prep(
    const void* __restrict__ nf, const int* __restrict__ cai,
    const void* __restrict__ Wq, const void* __restrict__ Wk, const void* __restrict__ Wv,
    const void* __restrict__ Wo,
    unsigned short* __restrict__ xg_hi, unsigned short* __restrict__ xg_lo,
    unsigned short* __restrict__ wqt_hi, unsigned short* __restrict__ wqt_lo,
    unsigned short* __restrict__ wot_hi, unsigned short* __restrict__ wot_lo,
    const int* __restrict__ flag)
{
    const bool f32 = *flag != 0;
    const int bid = blockIdx.x, tid = threadIdx.x;
    us4 h4, l4;
    if (bid < 1024) {
        int flat = bid*256 + tid;            // row*128 + kc
        int row = flat >> 7, kc = flat & 127;
        size_t src = (size_t)cai[row]*H_ + kc*4;
        #pragma unroll
        for (int i = 0; i < 4; i++) {
            float v = loadf(nf, src + i, f32);
            unsigned short hb = f2bf(v);
            h4[i] = hb; l4[i] = f2bf(v - bf2f(hb));
        }
        *(us4*)(xg_hi + (size_t)row*H_ + kc*4) = h4;
        *(us4*)(xg_lo + (size_t)row*H_ + kc*4) = l4;
    } else if (bid < 1792) {
        int flat = (bid-1024)*256 + tid;     // kc*1536 + nn
        int kc = flat / 1536, nn = flat - kc*1536;
        int mat = nn >> 9, ncol = nn & 511;
        const void* W = (mat==0) ? Wq : (mat==1) ? Wk : Wv;
        #pragma unroll
        for (int i = 0; i < 4; i++) {
            float v = loadf(W, (size_t)(kc*4+i)*H_ + ncol, f32);
            unsigned short hb = f2bf(v);
            h4[i] = hb; l4[i] = f2bf(v - bf2f(hb));
        }
        *(us4*)(wqt_hi + (size_t)nn*H_ + kc*4) = h4;
        *(us4*)(wqt_lo + (size_t)nn*H_ + kc*4) = l4;
    } else {
        int flat = (bid-1792)*256 + tid;     // kc*512 + n, kc 0..135
        int kc = flat >> 9, n = flat & 511;
        #pragma unroll
        for (int i = 0; i < 4; i++) {
            int k = kc*4 + i;
            float v = (k < 540) ? loadf(Wo, (size_t)k*H_ + n, f32) : 0.f;
            unsigned short hb = f2bf(v);
            h4[i] = hb; l4[i] = f2bf(v - bf2f(hb));
        }
        *(us4*)(wot_hi + (size_t)n*FA_LD + kc*4) = h4;
        *(us4*)(wot_lo + (size_t)n*FA_LD + kc*4) = l4;
    }
}

// ---------------------------------------------------------------- QKV MFMA GEMM (64x64, R23 verbatim)
__global__ __launch_bounds__(256) void qkv_mfma(
    const unsigned short* __restrict__ xg_hi, const unsigned short* __restrict__ xg_lo,
    const unsigned short* __restrict__ wqt_hi, const unsigned short* __restrict__ wqt_lo,
    const void* __restrict__ bq, const void* __restrict__ bk, const void* __restrict__ bv,
    unsigned short* __restrict__ qf, unsigned short* __restrict__ kf,
    unsigned short* __restrict__ vt, const int* __restrict__ flag)
{
    __shared__ __align__(16) char smem[17408];
    char* Xhi = smem;            // [64 rows][64B]
    char* Xlo = smem + 4096;
    char* Bhi = smem + 8192;
    char* Blo = smem + 12288;
    const int tid = threadIdx.x;
    const int w = tid >> 6, lane = tid & 63, cL = lane & 15, gL = lane >> 4;
    const int wm = w >> 1, wn = w & 1;
    const int mbase = blockIdx.x * 64;
    const int nblk  = blockIdx.y * 64;          // 0..1535
    const int mat = nblk >> 9, ncol0 = nblk & 511;
    const bool f32 = *flag != 0;
    const unsigned short* ahg = xg_hi + (size_t)mbase * H_;
    const unsigned short* alg = xg_lo + (size_t)mbase * H_;
    const unsigned short* bhg = wqt_hi + (size_t)nblk * H_;
    const unsigned short* blg = wqt_lo + (size_t)nblk * H_;

    u32x4 va[2], vb[2];
#define QKV_LOAD(K0)                                                          \
    {                                                                         \
        _Pragma("unroll")                                                     \
        for (int i = 0; i < 2; i++) {                                         \
            int flat = i*256 + tid, pl = flat >> 8, rem = flat & 255;         \
            int row = rem >> 2, c16 = rem & 3;                                \
            const unsigned short* pa = pl ? alg : ahg;                        \
            va[i] = *(const u32x4*)(pa + (size_t)row*H_ + (K0) + c16*8);      \
        }                                                                     \
        _Pragma("unroll")                                                     \
        for (int i = 0; i < 2; i++) {                                         \
            int flat = i*256 + tid, pl = flat >> 8, rem = flat & 255;         \
            int row = rem >> 2, c16 = rem & 3;                                \
            const unsigned short* pb = pl ? blg : bhg;                        \
            vb[i] = *(const u32x4*)(pb + (size_t)row*H_ + (K0) + c16*8);      \
        }                                                                     \
    }
    QKV_LOAD(0)
    f32x4 acc[2][2] = {};
    for (int kt = 0; kt < 16; kt++) {
        __syncthreads();
        #pragma unroll
        for (int i = 0; i < 2; i++) {
            int flat = i*256 + tid, pl = flat >> 8, rem = flat & 255;
            int row = rem >> 2, c16 = rem & 3;
            char* p = pl ? Xlo : Xhi;
            *(u32x4*)(p + row*64 + ((c16*16) ^ (((row>>1)&3)<<4))) = va[i];
        }
        #pragma unroll
        for (int i = 0; i < 2; i++) {
            int flat = i*256 + tid, pl = flat >> 8, rem = flat & 255;
            int row = rem >> 2, c16 = rem & 3;
            char* p = pl ? Blo : Bhi;
            *(u32x4*)(p + row*64 + ((c16*16) ^ (((row>>1)&3)<<4))) = vb[i];
        }
        __syncthreads();
        if (kt < 15) QKV_LOAD((kt+1)*32)
        bf16x8 ah[2], al[2], bh[2], bl[2];
        #pragma unroll
        for (int ms = 0; ms < 2; ms++) {
            int row = wm*32 + ms*16 + cL;
            int off = row*64 + ((gL*16) ^ (((row>>1)&3)<<4));
            ah[ms] = *(const bf16x8*)(Xhi + off);
            al[ms] = *(const bf16x8*)(Xlo + off);
        }
        #pragma unroll
        for (int ns = 0; ns < 2; ns++) {
            int row = wn*32 + ns*16 + cL;
            int off = row*64 + ((gL*16) ^ (((row>>1)&3)<<4));
            bh[ns] = *(const bf16x8*)(Bhi + off);
            bl[ns] = *(const bf16x8*)(Blo + off);
        }
        #pragma unroll
        for (int ms = 0; ms < 2; ms++)
            #pragma unroll
            for (int ns = 0; ns < 2; ns++) {
                acc[ms][ns] = __builtin_amdgcn_mfma_f32_16x16x32_bf16(ah[ms], bh[ns], acc[ms][ns], 0,0,0);
                acc[ms][ns] = __builtin_amdgcn_mfma_f32_16x16x32_bf16(ah[ms], bl[ns], acc[ms][ns], 0,0,0);
                acc[ms][ns] = __builtin_amdgcn_mfma_f32_16x16x32_bf16(al[ms], bh[ns], acc[ms][ns], 0,0,0);
            }
    }
#undef QKV_LOAD
    const void* bias = (mat==0) ? bq : (mat==1) ? bk : bv;
    if (mat == 2) {
        // V: direct transposed store  vt[col][2048]
        #pragma unroll
        for (int ns = 0; ns < 2; ns++) {
            int ncol = ncol0 + wn*32 + ns*16 + cL;
            float bc = loadf(bias, ncol, f32);
            #pragma unroll
            for (int ms = 0; ms < 2; ms++) {
                int m0 = mbase + wm*32 + ms*16 + gL*4;
                us4 pk;
                #pragma unroll
                for (int j = 0; j < 4; j++) pk[j] = f2bf(acc[ms][ns][j] + bc);
                *(us4*)(vt + (size_t)ncol*R_ + m0) = pk;
            }
        }
    } else {
        // Q/K: LDS transpose epilogue (one 32x32 pass per wave)
        unsigned short* dst = (mat==0) ? qf : kf;
        float* ep = (float*)smem + w*1088;     // [32][34] f32 per wave
        __syncthreads();
        #pragma unroll
        for (int ms = 0; ms < 2; ms++)
            #pragma unroll
            for (int ns = 0; ns < 2; ns++)
                #pragma unroll
                for (int j = 0; j < 4; j++)
                    ep[(ms*16 + gL*4 + j)*34 + ns*16 + cL] = acc[ms][ns][j];
        __syncthreads();
        int r = lane >> 1, cp = (lane & 1) * 16;
        int mrow = mbase + wm*32 + r;
        #pragma unroll
        for (int c4 = 0; c4 < 4; c4++) {
            int nloc = cp + c4*4;
            int ncol = ncol0 + wn*32 + nloc;
            us4 pk;
            #pragma unroll
            for (int e = 0; e < 4; e++)
                pk[e] = f2bf(ep[r*34 + nloc + e] + loadf(bias, ncol + e, f32));
            *(us4*)(dst + (size_t)mrow*H_ + ncol) = pk;
        }
    }
}

// ---------------------------------------------------------------- Wo MFMA GEMM (64x64, R23 verbatim)
__global__ __launch_bounds__(256) void wo_mfma(
    const float* __restrict__ fa,
    const unsigned short* __restrict__ wot_hi, const unsigned short* __restrict__ wot_lo,
    const void* __restrict__ bo, float* __restrict__ Y,
    const int* __restrict__ flag)
{
    __shared__ __align__(16) char smem[17408];
    char* Ahi = smem;
    char* Alo = smem + 4096;
    char* Bhi = smem + 8192;
    char* Blo = smem + 12288;
    const int tid = threadIdx.x;
    const int w = tid >> 6, lane = tid & 63, cL = lane & 15, gL = lane >> 4;
    const int wm = w >> 1, wn = w & 1;
    const int mbase = blockIdx.x * 64;
    const int nbase = blockIdx.y * 64;
    const bool f32 = *flag != 0;
    const unsigned short* bhg = wot_hi + (size_t)nbase * FA_LD;
    const unsigned short* blg = wot_lo + (size_t)nbase * FA_LD;

    float xv[8];
    u32x4 vb[2];
#define WO_LOAD(K0)                                                           \
    {                                                                         \
        _Pragma("unroll")                                                     \
        for (int i = 0; i < 2; i++) {                                         \
            int flat = i*256 + tid, row = flat >> 3, c4 = flat & 7;           \
            f32x4 t = *(const f32x4*)(fa + (size_t)(mbase+row)*FA_LD + (K0) + c4*4); \
            _Pragma("unroll")                                                 \
            for (int e = 0; e < 4; e++) xv[i*4+e] = t[e];                     \
        }                                                                     \
        _Pragma("unroll")                                                     \
        for (int i = 0; i < 2; i++) {                                         \
            int flat = i*256 + tid, pl = flat >> 8, rem = flat & 255;         \
            int row = rem >> 2, c16 = rem & 3;                                \
            const unsigned short* pb = pl ? blg : bhg;                        \
            vb[i] = *(const u32x4*)(pb + (size_t)row*FA_LD + (K0) + c16*8);   \
        }                                                                     \
    }
    WO_LOAD(0)
    f32x4 acc[2][2] = {};
    for (int kt = 0; kt < 17; kt++) {
        __syncthreads();
        #pragma unroll
        for (int i = 0; i < 2; i++) {
            int flat = i*256 + tid, row = flat >> 3, c4 = flat & 7;
            int sw = ((row>>1)&3) << 4;
            us4 h4, l4;
            #pragma unroll
            for (int e = 0; e < 4; e++) {
                float v = xv[i*4+e];
                unsigned short hb = f2bf(v);
                h4[e] = hb; l4[e] = f2bf(v - bf2f(hb));
            }
            *(us4*)(Ahi + row*64 + ((c4*8) ^ sw)) = h4;
            *(us4*)(Alo + row*64 + ((c4*8) ^ sw)) = l4;
        }
        #pragma unroll
        for (int i = 0; i < 2; i++) {
            int flat = i*256 + tid, pl = flat >> 8, rem = flat & 255;
            int row = rem >> 2, c16 = rem & 3;
            char* p = pl ? Blo : Bhi;
            *(u32x4*)(p + row*64 + ((c16*16) ^ (((row>>1)&3)<<4))) = vb[i];
        }
        __syncthreads();
        if (kt < 16) WO_LOAD((kt+1)*32)
        bf16x8 ah[2], al[2], bh[2], bl[2];
        #pragma unroll
        for (int ms = 0; ms < 2; ms++) {
            int row = wm*32 + ms*16 + cL;
            int off = row*64 + ((gL*16) ^ (((row>>1)&3)<<4));
            ah[ms] = *(const bf16x8*)(Ahi + off);
            al[ms] = *(const bf16x8*)(Alo + off);
        }
        #pragma unroll
        for (int ns = 0; ns < 2; ns++) {
            int row = wn*32 + ns*16 + cL;
            int off = row*64 + ((gL*16) ^ (((row>>1)&3)<<4));
            bh[ns] = *(const bf16x8*)(Bhi + off);
            bl[ns] = *(const bf16x8*)(Blo + off);
        }
        #pragma unroll
        for (int ms = 0; ms < 2; ms++)
            #pragma unroll
            for (int ns = 0; ns < 2; ns++) {
                acc[ms][ns] = __builtin_amdgcn_mfma_f32_16x16x32_bf16(ah[ms], bh[ns], acc[ms][ns], 0,0,0);
                acc[ms][ns] = __builtin_amdgcn_mfma_f32_16x16x32_bf16(ah[ms], bl[ns], acc[ms][ns], 0,0,0);
                acc[ms][ns] = __builtin_amdgcn_mfma_f32_16x16x32_bf16(al[ms], bh[ns], acc[ms][ns], 0,0,0);
            }
    }
#undef WO_LOAD
    // epilogue: LDS transpose, f32 store + bias
    float* ep = (float*)smem + w*1088;         // [32][34] f32 per wave
    __syncthreads();
    #pragma unroll
    for (int ms = 0; ms < 2; ms++)
        #pragma unroll
        for (int ns = 0; ns < 2; ns++)
            #pragma unroll
            for (int j = 0; j < 4; j++)
                ep[(ms*16 + gL*4 + j)*34 + ns*16 + cL] = acc[ms][ns][j];
    __syncthreads();
    int r = lane >> 1, cp = (lane & 1) * 16;
    int mrow = mbase + wm*32 + r;
    #pragma unroll
    for (int c4 = 0; c4 < 4; c4++) {
        int nloc = cp + c4*4;
        int ncol = nbase + wn*32 + nloc;
        f32x4 o;
        #pragma unroll
        for (int e = 0; e < 4; e++)
            o[e] = ep[r*34 + nloc + e] + loadf(bo, ncol + e, f32);
        *(f32x4*)(Y + (size_t)mrow*H_ + ncol) = o;
    }
}

// ---------------------------------------------------------------- attention v6: 16 waves, staged K + Ash alias + reg V
// grid (R/32, HEADS), 1024 threads = 16 waves. Wave w handles kt = w, w+16, ...
// LDS: per-wave K tile [32][256B] @ w*8192 (131072 total, Ash aliases own tile);
// reduction alias: Ored [16][32][68] f32 @0 (139264) + dred [16][32][4] @139264.
// Static LDS 147456 B. 1 block/CU, 4 waves/SIMD in main loop.
__global__ __launch_bounds__(1024, 1) void attn_mfma6(
    const unsigned short* __restrict__ qf, const unsigned short* __restrict__ kf,
    const unsigned short* __restrict__ vt,
    const f32x4* __restrict__ ca4, const float* __restrict__ maskf,
    const float* __restrict__ cb, const float* __restrict__ fr,
    float* __restrict__ fa)
{
    __shared__ __align__(16) char smem[147456];
    const int tid = threadIdx.x;
    const int w = tid >> 6, lane = tid & 63;
    const int cL = lane & 15, gL = lane >> 4;
    const int qbase = blockIdx.x * 32;
    const int h = blockIdx.y;

    char* KsW  = smem + w*8192;              // [32][256B] XOR-swizzled
    char* AshW = KsW;                        // ALIAS: P buffer reuses own K tile

    bf16x8 qfrag[2][4];
    #pragma unroll
    for (int mt = 0; mt < 2; mt++)
        #pragma unroll
        for (int ks = 0; ks < 4; ks++)
            qfrag[mt][ks] = *(const bf16x8*)(qf + (size_t)(qbase + mt*16 + cL)*H_
                                             + h*HD_ + ks*32 + gL*8);
    float mq[2][4];
    #pragma unroll
    for (int mt = 0; mt < 2; mt++)
        #pragma unroll
        for (int j = 0; j < 4; j++)
            mq[mt][j] = (maskf[qbase + mt*16 + gL*4 + j] > 0.f) ? 1.f : 0.f;

    f32x4 O[2][8] = {};
    float den[2][4] = {}, axv[2][4] = {}, ayv[2][4] = {}, azv[2][4] = {};

    const unsigned short* kbase = kf + h*HD_;
    const unsigned short* vbase = vt + (size_t)h*HD_*R_;

    for (int kt = w; kt < 64; kt += 16) {
        const int kb = kt * 32;
        u32x4 tK[8];
        #pragma unroll
        for (int j = 0; j < 8; j++) {
            int flat = j*64 + lane;
            tK[j] = *(const u32x4*)(kbase + (size_t)(kb + (flat>>4))*H_ + (flat&15)*8);
        }
        bf16x8 vreg[8];
        #pragma unroll
        for (int dt = 0; dt < 8; dt++)
            vreg[dt] = *(const bf16x8*)(vbase + (size_t)(dt*16 + cL)*R_ + kb + gL*8);
        f32x4 cav[2];
        #pragma unroll
        for (int nt = 0; nt < 2; nt++)
            cav[nt] = ca4[kb + nt*16 + cL];
        #pragma unroll
        for (int j = 0; j < 8; j++) {
            int flat = j*64 + lane;
            int row = flat>>4, c = flat&15;
            *(u32x4*)(KsW + row*256 + ((c*16) ^ ((row&7)<<4))) = tK[j];
        }
        f32x4 sacc[2][2] = {};
        #pragma unroll
        for (int nt = 0; nt < 2; nt++) {
            int n = nt*16 + cL;
            int rs = (n&7)<<4;
            bf16x8 k0 = *(const bf16x8*)(KsW + n*256 + (((0*4+gL)*16) ^ rs));
            bf16x8 k1 = *(const bf16x8*)(KsW + n*256 + (((1*4+gL)*16) ^ rs));
            bf16x8 k2 = *(const bf16x8*)(KsW + n*256 + (((2*4+gL)*16) ^ rs));
            bf16x8 k3 = *(const bf16x8*)(KsW + n*256 + (((3*4+gL)*16) ^ rs));
            #pragma unroll
            for (int mt = 0; mt < 2; mt++) {
                sacc[mt][nt] = __builtin_amdgcn_mfma_f32_16x16x32_bf16(qfrag[mt][0], k0, sacc[mt][nt], 0,0,0);
                sacc[mt][nt] = __builtin_amdgcn_mfma_f32_16x16x32_bf16(qfrag[mt][1], k1, sacc[mt][nt], 0,0,0);
                sacc[mt][nt] = __builtin_amdgcn_mfma_f32_16x16x32_bf16(qfrag[mt][2], k2, sacc[mt][nt], 0,0,0);
                sacc[mt][nt] = __builtin_amdgcn_mfma_f32_16x16x32_bf16(qfrag[mt][3], k3, sacc[mt][nt], 0,0,0);
            }
        }
        unsigned short* arow = (unsigned short*)AshW;
        #pragma unroll
        for (int nt = 0; nt < 2; nt++) {
            #pragma unroll
            for (int mt = 0; mt < 2; mt++) {
                f32x4 s4 = sacc[mt][nt];
                float av[4];
                #pragma unroll
                for (int j = 0; j < 4; j++) {
                    float a = __expf(fminf(s4[j], 75.f)) * cav[nt][3] * mq[mt][j];
                    if (!(a < 3.0e38f)) a = 0.f;
                    av[j] = a;
                    den[mt][j] += a;
                    axv[mt][j] += a * cav[nt][0];
                    ayv[mt][j] += a * cav[nt][1];
                    azv[mt][j] += a * cav[nt][2];
                }
                unsigned int p01, p23;
                asm("v_cvt_pk_bf16_f32 %0, %1, %2" : "=v"(p01) : "v"(av[0]), "v"(av[1]));
                asm("v_cvt_pk_bf16_f32 %0, %1, %2" : "=v"(p23) : "v"(av[2]), "v"(av[3]));
                int qr = mt*16 + gL*4;
                int col = nt*16 + cL;
                arow[(qr+0)*40 + col] = (unsigned short)p01;
                arow[(qr+1)*40 + col] = (unsigned short)(p01 >> 16);
                arow[(qr+2)*40 + col] = (unsigned short)p23;
                arow[(qr+3)*40 + col] = (unsigned short)(p23 >> 16);
            }
        }
        bf16x8 pa0 = *(const bf16x8*)(AshW + ((size_t)(cL)*40      + gL*8)*2);
        bf16x8 pa1 = *(const bf16x8*)(AshW + ((size_t)(16 + cL)*40 + gL*8)*2);
        #pragma unroll
        for (int dt = 0; dt < 8; dt++) {
            O[0][dt] = __builtin_amdgcn_mfma_f32_16x16x32_bf16(pa0, vreg[dt], O[0][dt], 0,0,0);
            O[1][dt] = __builtin_amdgcn_mfma_f32_16x16x32_bf16(pa1, vreg[dt], O[1][dt], 0,0,0);
        }
    }

    __syncthreads();
    float* Ored = (float*)smem;             // [16][32][68]
    float* dred = (float*)(smem + 139264);  // [16][32][4]
    #pragma unroll
    for (int mt = 0; mt < 2; mt++)
        #pragma unroll
        for (int j = 0; j < 4; j++) {
            float d0 = den[mt][j], x0 = axv[mt][j], y0 = ayv[mt][j], z0 = azv[mt][j];
            #pragma unroll
            for (int off = 8; off >= 1; off >>= 1) {
                d0 += __shfl_xor(d0, off); x0 += __shfl_xor(x0, off);
                y0 += __shfl_xor(y0, off); z0 += __shfl_xor(z0, off);
            }
            if (cL == 0) {
                f32x4 v; v[0]=d0; v[1]=x0; v[2]=y0; v[3]=z0;
                *(f32x4*)&dred[w*128 + (mt*16 + gL*4 + j)*4] = v;
            }
        }
    #pragma unroll
    for (int mt = 0; mt < 2; mt++)
        #pragma unroll
        for (int dtl = 0; dtl < 4; dtl++) {
            f32x4 o4 = O[mt][dtl];
            #pragma unroll
            for (int j = 0; j < 4; j++)
                Ored[w*2176 + (mt*16 + gL*4 + j)*68 + dtl*16 + cL] = o4[j];
        }
    __syncthreads();
    if (tid < 512) {
        int q = tid >> 4, c4 = (tid & 15) * 4;
        float dn = 0.f;
        #pragma unroll
        for (int ww = 0; ww < 16; ww++) dn += dred[ww*128 + q*4];
        float inv = (dn > 0.f) ? 1.f/dn : 0.f;
        f32x4 s = *(const f32x4*)&Ored[q*68 + c4];
        #pragma unroll
        for (int ww = 1; ww < 16; ww++)
            s += *(const f32x4*)&Ored[ww*2176 + q*68 + c4];
        *(f32x4*)&fa[(size_t)(qbase+q)*FA_LD + h*HD_ + c4] = s * inv;
    }
    if (tid < 32) {
        float dn=0.f, ax=0.f, ay=0.f, az=0.f;
        #pragma unroll
        for (int ww = 0; ww < 16; ww++) {
            const float* dp = &dred[ww*128 + tid*4];
            dn += dp[0]; ax += dp[1]; ay += dp[2]; az += dp[3];
        }
        float inv = (dn > 0.f) ? 1.f/dn : 0.f;
        float live = (dn > 0.f) ? 1.f : 0.f;
        int qg = qbase + tid;
        float b0 = cb[qg*3+0]*live - ax*inv;
        float b1 = cb[qg*3+1]*live - ay*inv;
        float b2 = cb[qg*3+2]*live - az*inv;
        float dist = sqrtf(b0*b0 + b1*b1 + b2*b2);
        const float* F = fr + (size_t)qg*9;
        float p0 = F[0]*b0 + F[1]*b1 + F[2]*b2;
        float p1 = F[3]*b0 + F[4]*b1 + F[5]*b2;
        float p2 = F[6]*b0 + F[7]*b1 + F[8]*b2;
        float pn = sqrtf(p0*p0 + p1*p1 + p2*p2) + 1e-10f;
        size_t rb = (size_t)qg * FA_LD;
        fa[rb + 512 + h*3 + 0] = p0;
        fa[rb + 512 + h*3 + 1] = p1;
        fa[rb + 512 + h*3 + 2] = p2;
        fa[rb + 524 + h]       = dist;
        fa[rb + 528 + h*3 + 0] = p0/pn;
        fa[rb + 528 + h*3 + 1] = p1/pn;
        fa[rb + 528 + h*3 + 2] = p2/pn;
        if (h == 0) { fa[rb+540]=0.f; fa[rb+541]=0.f; fa[rb+542]=0.f; fa[rb+543]=0.f; }
    }
    __syncthreads();
    #pragma unroll
    for (int mt = 0; mt < 2; mt++)
        #pragma unroll
        for (int dtl = 0; dtl < 4; dtl++) {
            f32x4 o4 = O[mt][4 + dtl];
            #pragma unroll
            for (int j = 0; j < 4; j++)
                Ored[w*2176 + (mt*16 + gL*4 + j)*68 + dtl*16 + cL] = o4[j];
        }
    __syncthreads();
    if (tid < 512) {
        int q = tid >> 4, c4 = (tid & 15) * 4;
        float dn = 0.f;
        #pragma unroll
        for (int ww = 0; ww < 16; ww++) dn += dred[ww*128 + q*4];
        float inv = (dn > 0.f) ? 1.f/dn : 0.f;
        f32x4 s = *(const f32x4*)&Ored[q*68 + c4];
        #pragma unroll
        for (int ww = 1; ww < 16; ww++)
            s += *(const f32x4*)&Ored[ww*2176 + q*68 + c4];
        *(f32x4*)&fa[(size_t)(qbase+q)*FA_LD + h*HD_ + 64 + c4] = s * inv;
    }
}

// ---------------------------------------------------------------- relu+LN1+mask+res+LN2 (R17 verbatim)
__global__ __launch_bounds__(256) void final_ln(
    const float* __restrict__ Y, const void* __restrict__ nf,
    const int* __restrict__ cai, const float* __restrict__ maskf,
    const void* __restrict__ g1, const void* __restrict__ b1,
    const void* __restrict__ g2, const void* __restrict__ b2,
    void* __restrict__ out, const int* __restrict__ flag)
{
    const int tid = threadIdx.x, lane = tid & 63, wave = tid >> 6;
    const int r = blockIdx.x * 4 + wave;
    bool f32 = *flag != 0;
    const float mk = maskf[r];
    const size_t xrow = (size_t)cai[r] * H_;
    float y[8], s1 = 0.f, s2 = 0.f;
    #pragma unroll
    for (int i = 0; i < 8; i++) {
        int c = lane + i*64;
        float v = fmaxf(Y[(size_t)r*H_ + c], 0.f);
        y[i] = v; s1 += v; s2 += v*v;
    }
    #pragma unroll
    for (int off = 32; off; off >>= 1) { s1 += __shfl_xor(s1, off); s2 += __shfl_xor(s2, off); }
    float mu = s1 * (1.f/H_);
    float var = s2 * (1.f/H_) - mu*mu;
    float rstd = rsqrtf(fmaxf(var, 0.f) + 1e-5f);
    float t[8], u1 = 0.f, u2 = 0.f;
    #pragma unroll
    for (int i = 0; i < 8; i++) {
        int c = lane + i*64;
        float hh = (y[i]-mu)*rstd*loadf(g1, c, f32) + loadf(b1, c, f32);
        hh *= mk;
        float tv = loadf(nf, xrow + c, f32) + hh;
        t[i] = tv; u1 += tv; u2 += tv*tv;
    }
    #pragma unroll
    for (int off = 32; off; off >>= 1) { u1 += __shfl_xor(u1, off); u2 += __shfl_xor(u2, off); }
    float mu2 = u1 * (1.f/H_);
    float var2 = u2 * (1.f/H_) - mu2*mu2;
    float rstd2 = rsqrtf(fmaxf(var2, 0.f) + 1e-5f);
    #pragma unroll
    for (int i = 0; i < 8; i++) {
        int c = lane + i*64;
        float ov = (t[i]-mu2)*rstd2*loadf(g2, c, f32) + loadf(b2, c, f32);
        if (f32) ((float*)out)[(size_t)r*H_ + c] = ov;
        else ((unsigned short*)out)[(size_t)r*H_ + c] = f2bf(ov);
    }
}

// ---------------------------------------------------------------- launch
extern "C" void kernel_launch(void* const* d_in, const int* in_sizes, int n_in,
                              void* d_out, int out_size, void* d_ws, size_t ws_size,
                              hipStream_t stream)
{
    static const int expected[16] = {
        8388608, 49152, 262144, 512, 262144, 512, 262144, 512,
        276480, 512, 512, 512, 512, 512, 16384, 16384
    };
    if (n_in != 16) {
        diag<<<dim3(1), dim3(64), 0, stream>>>((unsigned short*)d_out, 1000.f + n_in);
        return;
    }
    for (int i = 0; i < 16; i++) {
        if (in_sizes[i] != expected[i]) {
            diag<<<dim3(1), dim3(64), 0, stream>>>((unsigned short*)d_out, 2000.f + 10.f*i);
            return;
        }
    }
    const size_t need = 16056320;
    if (ws_size < need) {
        diag<<<dim3(1), dim3(64), 0, stream>>>((unsigned short*)d_out, 3000.f);
        return;
    }

    const void* nf  = d_in[0];
    const void* pos = d_in[1];
    const void* Wq  = d_in[2];  const void* bq = d_in[3];
    const void* Wk  = d_in[4];  const void* bk = d_in[5];
    const void* Wv  = d_in[6];  const void* bv = d_in[7];
    const void* Wo  = d_in[8];  const void* bo = d_in[9];
    const void* g1  = d_in[10]; const void* b1 = d_in[11];
    const void* g2  = d_in[12]; const void* b2 = d_in[13];
    const int* atype = (const int*)d_in[14];

    char* ws = (char*)d_ws;
    int*   flag  = (int*)  (ws + 0);
    int*   cai   = (int*)  (ws + 1024);
    float* ca    = (float*)(ws + 9216);
    float* cb    = (float*)(ws + 33792);
    float* fr    = (float*)(ws + 58368);
    float* maskf = (float*)(ws + 132096);
    f32x4* ca4   = (f32x4*)(ws + 140288);                   // [2048] (ca.xyz, mask)
    unsigned short* qf = (unsigned short*)(ws + 1048576);
    unsigned short* kf = (unsigned short*)(ws + 3145728);
    unsigned short* vt = (unsigned short*)(ws + 5242880);   // [512][2048] bf16
    unsigned short* xg_hi = (unsigned short*)(ws + 7340032);
    unsigned short* xg_lo = (unsigned short*)(ws + 9437184);
    float* fa = (float*)(ws + 7340032);                     // [2048][544] f32 (aliases xg)
    unsigned short* wqt_hi = (unsigned short*)(ws + 11796480);
    unsigned short* wqt_lo = (unsigned short*)(ws + 13369344);
    unsigned short* wot_hi = (unsigned short*)(ws + 14942208);
    unsigned short* wot_lo = (unsigned short*)(ws + 15499264);
    float* Y  = (float*)qf;   // aliases qf+kf (4 MB) — both dead after attn

    detect_dtype<<<dim3(1), dim3(256), 0, stream>>>((const unsigned short*)nf, flag);
    gather_frames<<<dim3(8), dim3(256), 0, stream>>>(pos, atype, flag, cai, ca, cb, fr,
                                                     maskf, ca4);
    pack_prep<<<dim3(2064), dim3(256), 0, stream>>>(nf, cai, Wq, Wk, Wv, Wo,
                                                    xg_hi, xg_lo, wqt_hi, wqt_lo,
                                                    wot_hi, wot_lo, flag);
    qkv_mfma<<<dim3(32, 24), dim3(256), 0, stream>>>(xg_hi, xg_lo, wqt_hi, wqt_lo,
                                                     bq, bk, bv, qf, kf, vt, flag);
    attn_mfma6<<<dim3(R_/32, HEADS_), dim3(1024), 0, stream>>>(qf, kf, vt, ca4, maskf,
                                                               cb, fr, fa);
    wo_mfma<<<dim3(32, 8), dim3(256), 0, stream>>>(fa, wot_hi, wot_lo, bo, Y, flag);
    final_ln<<<dim3(512), dim3(256), 0, stream>>>(Y, nf, cai, maskf, g1, b1, g2, b2,
                                                  d_out, flag);
}

// Round 11
// 184.301 us; speedup vs baseline: 1.5197x; 1.5197x over previous
//
#include <hip/hip_runtime.h>
#include <hip/hip_bf16.h>
#include <stdint.h>

// GeometricGNN on MI355X. R=2048, APR=8, H=512, HEADS=4, HD=128, SD=28.
// Round 28: R26 (best, 188.2us) with front-end consolidated:
//  - prep_all = detect_dtype + gather_frames + pack_prep in ONE dispatch
//    (grid 2072). Every block recomputes the dtype flag inline
//    (deterministic); pack-X blocks recompute cai inline from atype.
//    7 kernels -> 5: measures/removes 2 launch gaps.
//  - qkv_mfma / attn_mfma3(Ash-alias) / wo_mfma / final_ln: R26 verbatim.

#define R_ 2048
#define APR_ 8
#define H_ 512
#define HEADS_ 4
#define HD_ 128
#define FA_LD 544

typedef __attribute__((ext_vector_type(4))) float f32x4;
typedef __attribute__((ext_vector_type(4))) unsigned int u32x4;
typedef __attribute__((ext_vector_type(4))) unsigned short us4;
typedef __bf16 bf16x8 __attribute__((ext_vector_type(8)));

static __device__ __forceinline__ float bf2f(unsigned short u) {
    union { unsigned int i; float f; } c; c.i = ((unsigned int)u) << 16; return c.f;
}
static __device__ __forceinline__ unsigned short f2bf(float f) {
    union { float f; unsigned int i; } c; c.f = f;
    unsigned int r = c.i + 0x7fffu + ((c.i >> 16) & 1u);   // RNE
    return (unsigned short)(r >> 16);
}
// flag-aware, sanitized load of logical element i of a float input array
static __device__ __forceinline__ float loadf(const void* p, size_t i, bool f32) {
    float v = f32 ? ((const float*)p)[i] : bf2f(((const unsigned short*)p)[i]);
    return (v == v && fabsf(v) < 1e30f) ? v : 0.f;
}

// ---------------------------------------------------------------- diag
__global__ void diag(unsigned short* out, float val) {
    if (threadIdx.x == 0 && blockIdx.x == 0) out[0] = f2bf(val);
}

// ---------------------------------------------------------------- prep_all
// grid 2072 x 256. Each block: inline dtype detect (identical arithmetic to
// old detect_dtype), then:
//   bid 0..7      : gather_frames body (block 0 also publishes flag)
//   bid 8..1031   : pack X rows -> xg_hi/lo (cai recomputed inline)
//   bid 1032..1799: transpose+split Wqkv -> wqt_hi/lo
//   bid 1800..2071: transpose+split+pad Wo -> wot_hi/lo
__global__ __launch_bounds__(256) void prep_all(
    const void* __restrict__ nf, const void* __restrict__ pos,
    const int* __restrict__ atype,
    const void* __restrict__ Wq, const void* __restrict__ Wk, const void* __restrict__ Wv,
    const void* __restrict__ Wo,
    int* __restrict__ flag, int* __restrict__ cai,
    float* __restrict__ ca, float* __restrict__ cb, float* __restrict__ fr,
    float* __restrict__ maskf, f32x4* __restrict__ ca4,
    unsigned short* __restrict__ xg_hi, unsigned short* __restrict__ xg_lo,
    unsigned short* __restrict__ wqt_hi, unsigned short* __restrict__ wqt_lo,
    unsigned short* __restrict__ wot_hi, unsigned short* __restrict__ wot_lo)
{
    __shared__ int bad;
    const int bid = blockIdx.x, tid = threadIdx.x;
    if (tid == 0) bad = 0;
    __syncthreads();
    {
        const unsigned short* nfu = (const unsigned short*)nf;
        int cnt = 0;
        for (int i = tid; i < 8192; i += 256) {
            unsigned e = (nfu[i] >> 7) & 0xFFu;
            if (e >= 0xC0u) cnt++;
        }
        #pragma unroll
        for (int off = 32; off; off >>= 1) cnt += __shfl_xor(cnt, off);
        if ((tid & 63) == 0) atomicAdd(&bad, cnt);
    }
    __syncthreads();
    const bool f32 = bad > 16;

    if (bid < 8) {
        // ---------- gather_frames body ----------
        int r = bid * 256 + tid;
        if (bid == 0 && tid == 0) *flag = f32 ? 1 : 0;
        if (r >= R_) return;
        int base = r * APR_;
        float caP[3] = {0,0,0}, cbP[3] = {0,0,0};
        int idx = base; bool h0=false, h1=false, h2=false;
        for (int a = 0; a < APR_; a++) {
            int t = atype[base + a];
            if (t == 0) h0 = true;
            if (t == 2) h2 = true;
            if (t == 1) { h1 = true; idx = base + a;
                for (int j = 0; j < 3; j++) caP[j] += loadf(pos, (size_t)(base+a)*3 + j, f32); }
            if (t == 4) {
                for (int j = 0; j < 3; j++) cbP[j] += loadf(pos, (size_t)(base+a)*3 + j, f32); }
        }
        float s = fabsf(cbP[0]) + fabsf(cbP[1]) + fabsf(cbP[2]);
        if (s < 1e-6f) { cbP[0]=caP[0]; cbP[1]=caP[1]; cbP[2]=caP[2]; }
        float e1[3] = { cbP[0]-caP[0], cbP[1]-caP[1], cbP[2]-caP[2] };
        float n1 = sqrtf(e1[0]*e1[0] + e1[1]*e1[1] + e1[2]*e1[2]);
        float e1u[3] = { e1[0], e1[1], e1[2] };
        if (n1 > 1e-6f) { float iv = 1.f / fmaxf(n1, 1e-6f); e1u[0]*=iv; e1u[1]*=iv; e1u[2]*=iv; }
        float e2a[3] = { e1u[1], -e1u[0], 0.f };
        float n2a = sqrtf(e2a[0]*e2a[0] + e2a[1]*e2a[1]);
        float e2b[3] = { -e1u[2], 0.f, e1u[0] };
        float n2b = sqrtf(e2b[0]*e2b[0] + e2b[2]*e2b[2]);
        bool useb = n2a < 1e-6f;
        float e2[3] = { useb?e2b[0]:e2a[0], useb?e2b[1]:e2a[1], useb?e2b[2]:e2a[2] };
        float n2 = useb ? n2b : n2a;
        float iv2 = 1.f / fmaxf(n2, 1e-6f);
        float e2u[3] = { e2[0]*iv2, e2[1]*iv2, e2[2]*iv2 };
        float e3[3] = { e1u[1]*e2u[2]-e1u[2]*e2u[1],
                        e1u[2]*e2u[0]-e1u[0]*e2u[2],
                        e1u[0]*e2u[1]-e1u[1]*e2u[0] };
        bool ok = (r < R_-1) && (n1 > 1e-6f) && (n2 > 1e-6f);
        float F[9];
        if (ok) { F[0]=e1u[0]; F[1]=e2u[0]; F[2]=e3[0];
                  F[3]=e1u[1]; F[4]=e2u[1]; F[5]=e3[1];
                  F[6]=e1u[2]; F[7]=e2u[2]; F[8]=e3[2]; }
        else    { F[0]=1;F[1]=0;F[2]=0; F[3]=0;F[4]=1;F[5]=0; F[6]=0;F[7]=0;F[8]=1; }
        cai[r] = idx;
        for (int j = 0; j < 3; j++) { ca[r*3+j] = caP[j]; cb[r*3+j] = cbP[j]; }
        for (int j = 0; j < 9; j++) fr[r*9+j] = F[j];
        float mk = (h0 && h1 && h2) ? 1.f : 0.f;
        maskf[r] = mk;
        f32x4 c4; c4[0]=caP[0]; c4[1]=caP[1]; c4[2]=caP[2]; c4[3]=mk;
        ca4[r] = c4;
        return;
    }

    us4 h4, l4;
    if (bid < 1032) {
        // ---------- pack X rows (cai inline) ----------
        int flat = (bid-8)*256 + tid;        // row*128 + kc
        int row = flat >> 7, kc = flat & 127;
        int base = row * APR_, idx = base;
        #pragma unroll
        for (int a = 0; a < APR_; a++)
            if (atype[base + a] == 1) idx = base + a;
        size_t src = (size_t)idx*H_ + kc*4;
        #pragma unroll
        for (int i = 0; i < 4; i++) {
            float v = loadf(nf, src + i, f32);
            unsigned short hb = f2bf(v);
            h4[i] = hb; l4[i] = f2bf(v - bf2f(hb));
        }
        *(us4*)(xg_hi + (size_t)row*H_ + kc*4) = h4;
        *(us4*)(xg_lo + (size_t)row*H_ + kc*4) = l4;
    } else if (bid < 1800) {
        int flat = (bid-1032)*256 + tid;     // kc*1536 + nn
        int kc = flat / 1536, nn = flat - kc*1536;
        int mat = nn >> 9, ncol = nn & 511;
        const void* W = (mat==0) ? Wq : (mat==1) ? Wk : Wv;
        #pragma unroll
        for (int i = 0; i < 4; i++) {
            float v = loadf(W, (size_t)(kc*4+i)*H_ + ncol, f32);
            unsigned short hb = f2bf(v);
            h4[i] = hb; l4[i] = f2bf(v - bf2f(hb));
        }
        *(us4*)(wqt_hi + (size_t)nn*H_ + kc*4) = h4;
        *(us4*)(wqt_lo + (size_t)nn*H_ + kc*4) = l4;
    } else {
        int flat = (bid-1800)*256 + tid;     // kc*512 + n, kc 0..135
        int kc = flat >> 9, n = flat & 511;
        #pragma unroll
        for (int i = 0; i < 4; i++) {
            int k = kc*4 + i;
            float v = (k < 540) ? loadf(Wo, (size_t)k*H_ + n, f32) : 0.f;
            unsigned short hb = f2bf(v);
            h4[i] = hb; l4[i] = f2bf(v - bf2f(hb));
        }
        *(us4*)(wot_hi + (size_t)n*FA_LD + kc*4) = h4;
        *(us4*)(wot_lo + (size_t)n*FA_LD + kc*4) = l4;
    }
}

// ---------------------------------------------------------------- QKV MFMA GEMM (64x64, R23 verbatim)
__global__ __launch_bounds__(256) void qkv_mfma(
    const unsigned short* __restrict__ xg_hi, const unsigned short* __restrict__ xg_lo,
    const unsigned short* __restrict__ wqt_hi, const unsigned short* __restrict__ wqt_lo,
    const void* __restrict__ bq, const void* __restrict__ bk, const void* __restrict__ bv,
    unsigned short* __restrict__ qf, unsigned short* __restrict__ kf,
    unsigned short* __restrict__ vt, const int* __restrict__ flag)
{
    __shared__ __align__(16) char smem[17408];
    char* Xhi = smem;            // [64 rows][64B]
    char* Xlo = smem + 4096;
    char* Bhi = smem + 8192;
    char* Blo = smem + 12288;
    const int tid = threadIdx.x;
    const int w = tid >> 6, lane = tid & 63, cL = lane & 15, gL = lane >> 4;
    const int wm = w >> 1, wn = w & 1;
    const int mbase = blockIdx.x * 64;
    const int nblk  = blockIdx.y * 64;          // 0..1535
    const int mat = nblk >> 9, ncol0 = nblk & 511;
    const bool f32 = *flag != 0;
    const unsigned short* ahg = xg_hi + (size_t)mbase * H_;
    const unsigned short* alg = xg_lo + (size_t)mbase * H_;
    const unsigned short* bhg = wqt_hi + (size_t)nblk * H_;
    const unsigned short* blg = wqt_lo + (size_t)nblk * H_;

    u32x4 va[2], vb[2];
#define QKV_LOAD(K0)                                                          \
    {                                                                         \
        _Pragma("unroll")                                                     \
        for (int i = 0; i < 2; i++) {                                         \
            int flat = i*256 + tid, pl = flat >> 8, rem = flat & 255;         \
            int row = rem >> 2, c16 = rem & 3;                                \
            const unsigned short* pa = pl ? alg : ahg;                        \
            va[i] = *(const u32x4*)(pa + (size_t)row*H_ + (K0) + c16*8);      \
        }                                                                     \
        _Pragma("unroll")                                                     \
        for (int i = 0; i < 2; i++) {                                         \
            int flat = i*256 + tid, pl = flat >> 8, rem = flat & 255;         \
            int row = rem >> 2, c16 = rem & 3;                                \
            const unsigned short* pb = pl ? blg : bhg;                        \
            vb[i] = *(const u32x4*)(pb + (size_t)row*H_ + (K0) + c16*8);      \
        }                                                                     \
    }
    QKV_LOAD(0)
    f32x4 acc[2][2] = {};
    for (int kt = 0; kt < 16; kt++) {
        __syncthreads();
        #pragma unroll
        for (int i = 0; i < 2; i++) {
            int flat = i*256 + tid, pl = flat >> 8, rem = flat & 255;
            int row = rem >> 2, c16 = rem & 3;
            char* p = pl ? Xlo : Xhi;
            *(u32x4*)(p + row*64 + ((c16*16) ^ (((row>>1)&3)<<4))) = va[i];
        }
        #pragma unroll
        for (int i = 0; i < 2; i++) {
            int flat = i*256 + tid, pl = flat >> 8, rem = flat & 255;
            int row = rem >> 2, c16 = rem & 3;
            char* p = pl ? Blo : Bhi;
            *(u32x4*)(p + row*64 + ((c16*16) ^ (((row>>1)&3)<<4))) = vb[i];
        }
        __syncthreads();
        if (kt < 15) QKV_LOAD((kt+1)*32)
        bf16x8 ah[2], al[2], bh[2], bl[2];
        #pragma unroll
        for (int ms = 0; ms < 2; ms++) {
            int row = wm*32 + ms*16 + cL;
            int off = row*64 + ((gL*16) ^ (((row>>1)&3)<<4));
            ah[ms] = *(const bf16x8*)(Xhi + off);
            al[ms] = *(const bf16x8*)(Xlo + off);
        }
        #pragma unroll
        for (int ns = 0; ns < 2; ns++) {
            int row = wn*32 + ns*16 + cL;
            int off = row*64 + ((gL*16) ^ (((row>>1)&3)<<4));
            bh[ns] = *(const bf16x8*)(Bhi + off);
            bl[ns] = *(const bf16x8*)(Blo + off);
        }
        #pragma unroll
        for (int ms = 0; ms < 2; ms++)
            #pragma unroll
            for (int ns = 0; ns < 2; ns++) {
                acc[ms][ns] = __builtin_amdgcn_mfma_f32_16x16x32_bf16(ah[ms], bh[ns], acc[ms][ns], 0,0,0);
                acc[ms][ns] = __builtin_amdgcn_mfma_f32_16x16x32_bf16(ah[ms], bl[ns], acc[ms][ns], 0,0,0);
                acc[ms][ns] = __builtin_amdgcn_mfma_f32_16x16x32_bf16(al[ms], bh[ns], acc[ms][ns], 0,0,0);
            }
    }
#undef QKV_LOAD
    const void* bias = (mat==0) ? bq : (mat==1) ? bk : bv;
    if (mat == 2) {
        // V: direct transposed store  vt[col][2048]
        #pragma unroll
        for (int ns = 0; ns < 2; ns++) {
            int ncol = ncol0 + wn*32 + ns*16 + cL;
            float bc = loadf(bias, ncol, f32);
            #pragma unroll
            for (int ms = 0; ms < 2; ms++) {
                int m0 = mbase + wm*32 + ms*16 + gL*4;
                us4 pk;
                #pragma unroll
                for (int j = 0; j < 4; j++) pk[j] = f2bf(acc[ms][ns][j] + bc);
                *(us4*)(vt + (size_t)ncol*R_ + m0) = pk;
            }
        }
    } else {
        // Q/K: LDS transpose epilogue (one 32x32 pass per wave)
        unsigned short* dst = (mat==0) ? qf : kf;
        float* ep = (float*)smem + w*1088;     // [32][34] f32 per wave
        __syncthreads();
        #pragma unroll
        for (int ms = 0; ms < 2; ms++)
            #pragma unroll
            for (int ns = 0; ns < 2; ns++)
                #pragma unroll
                for (int j = 0; j < 4; j++)
                    ep[(ms*16 + gL*4 + j)*34 + ns*16 + cL] = acc[ms][ns][j];
        __syncthreads();
        int r = lane >> 1, cp = (lane & 1) * 16;
        int mrow = mbase + wm*32 + r;
        #pragma unroll
        for (int c4 = 0; c4 < 4; c4++) {
            int nloc = cp + c4*4;
            int ncol = ncol0 + wn*32 + nloc;
            us4 pk;
            #pragma unroll
            for (int e = 0; e < 4; e++)
                pk[e] = f2bf(ep[r*34 + nloc + e] + loadf(bias, ncol + e, f32));
            *(us4*)(dst + (size_t)mrow*H_ + ncol) = pk;
        }
    }
}

// ---------------------------------------------------------------- Wo MFMA GEMM (64x64, R23 verbatim)
__global__ __launch_bounds__(256) void wo_mfma(
    const float* __restrict__ fa,
    const unsigned short* __restrict__ wot_hi, const unsigned short* __restrict__ wot_lo,
    const void* __restrict__ bo, float* __restrict__ Y,
    const int* __restrict__ flag)
{
    __shared__ __align__(16) char smem[17408];
    char* Ahi = smem;
    char* Alo = smem + 4096;
    char* Bhi = smem + 8192;
    char* Blo = smem + 12288;
    const int tid = threadIdx.x;
    const int w = tid >> 6, lane = tid & 63, cL = lane & 15, gL = lane >> 4;
    const int wm = w >> 1, wn = w & 1;
    const int mbase = blockIdx.x * 64;
    const int nbase = blockIdx.y * 64;
    const bool f32 = *flag != 0;
    const unsigned short* bhg = wot_hi + (size_t)nbase * FA_LD;
    const unsigned short* blg = wot_lo + (size_t)nbase * FA_LD;

    float xv[8];
    u32x4 vb[2];
#define WO_LOAD(K0)                                                           \
    {                                                                         \
        _Pragma("unroll")                                                     \
        for (int i = 0; i < 2; i++) {                                         \
            int flat = i*256 + tid, row = flat >> 3, c4 = flat & 7;           \
            f32x4 t = *(const f32x4*)(fa + (size_t)(mbase+row)*FA_LD + (K0) + c4*4); \
            _Pragma("unroll")                                                 \
            for (int e = 0; e < 4; e++) xv[i*4+e] = t[e];                     \
        }                                                                     \
        _Pragma("unroll")                                                     \
        for (int i = 0; i < 2; i++) {                                         \
            int flat = i*256 + tid, pl = flat >> 8, rem = flat & 255;         \
            int row = rem >> 2, c16 = rem & 3;                                \
            const unsigned short* pb = pl ? blg : bhg;                        \
            vb[i] = *(const u32x4*)(pb + (size_t)row*FA_LD + (K0) + c16*8);   \
        }                                                                     \
    }
    WO_LOAD(0)
    f32x4 acc[2][2] = {};
    for (int kt = 0; kt < 17; kt++) {
        __syncthreads();
        #pragma unroll
        for (int i = 0; i < 2; i++) {
            int flat = i*256 + tid, row = flat >> 3, c4 = flat & 7;
            int sw = ((row>>1)&3) << 4;
            us4 h4, l4;
            #pragma unroll
            for (int e = 0; e < 4; e++) {
                float v = xv[i*4+e];
                unsigned short hb = f2bf(v);
                h4[e] = hb; l4[e] = f2bf(v - bf2f(hb));
            }
            *(us4*)(Ahi + row*64 + ((c4*8) ^ sw)) = h4;
            *(us4*)(Alo + row*64 + ((c4*8) ^ sw)) = l4;
        }
        #pragma unroll
        for (int i = 0; i < 2; i++) {
            int flat = i*256 + tid, pl = flat >> 8, rem = flat & 255;
            int row = rem >> 2, c16 = rem & 3;
            char* p = pl ? Blo : Bhi;
            *(u32x4*)(p + row*64 + ((c16*16) ^ (((row>>1)&3)<<4))) = vb[i];
        }
        __syncthreads();
        if (kt < 16) WO_LOAD((kt+1)*32)
        bf16x8 ah[2], al[2], bh[2], bl[2];
        #pragma unroll
        for (int ms = 0; ms < 2; ms++) {
            int row = wm*32 + ms*16 + cL;
            int off = row*64 + ((gL*16) ^ (((row>>1)&3)<<4));
            ah[ms] = *(const bf16x8*)(Ahi + off);
            al[ms] = *(const bf16x8*)(Alo + off);
        }
        #pragma unroll
        for (int ns = 0; ns < 2; ns++) {
            int row = wn*32 + ns*16 + cL;
            int off = row*64 + ((gL*16) ^ (((row>>1)&3)<<4));
            bh[ns] = *(const bf16x8*)(Bhi + off);
            bl[ns] = *(const bf16x8*)(Blo + off);
        }
        #pragma unroll
        for (int ms = 0; ms < 2; ms++)
            #pragma unroll
            for (int ns = 0; ns < 2; ns++) {
                acc[ms][ns] = __builtin_amdgcn_mfma_f32_16x16x32_bf16(ah[ms], bh[ns], acc[ms][ns], 0,0,0);
                acc[ms][ns] = __builtin_amdgcn_mfma_f32_16x16x32_bf16(ah[ms], bl[ns], acc[ms][ns], 0,0,0);
                acc[ms][ns] = __builtin_amdgcn_mfma_f32_16x16x32_bf16(al[ms], bh[ns], acc[ms][ns], 0,0,0);
            }
    }
#undef WO_LOAD
    // epilogue: LDS transpose, f32 store + bias
    float* ep = (float*)smem + w*1088;         // [32][34] f32 per wave
    __syncthreads();
    #pragma unroll
    for (int ms = 0; ms < 2; ms++)
        #pragma unroll
        for (int ns = 0; ns < 2; ns++)
            #pragma unroll
            for (int j = 0; j < 4; j++)
                ep[(ms*16 + gL*4 + j)*34 + ns*16 + cL] = acc[ms][ns][j];
    __syncthreads();
    int r = lane >> 1, cp = (lane & 1) * 16;
    int mrow = mbase + wm*32 + r;
    #pragma unroll
    for (int c4 = 0; c4 < 4; c4++) {
        int nloc = cp + c4*4;
        int ncol = nbase + wn*32 + nloc;
        f32x4 o;
        #pragma unroll
        for (int e = 0; e < 4; e++)
            o[e] = ep[r*34 + nloc + e] + loadf(bo, ncol + e, f32);
        *(f32x4*)(Y + (size_t)mrow*H_ + ncol) = o;
    }
}

// ---------------------------------------------------------------- attention v3b (R26 verbatim)
// grid (R/32, HEADS), 512 threads = 8 waves. Wave w handles kt = w, w+8, ...
// LDS: per-wave K tile [32][256B] @ w*8192 (64KB total); Ash aliases own tile.
// Static LDS = reduction alias 73728 B.
__global__ __launch_bounds__(512, 1) void attn_mfma3(
    const unsigned short* __restrict__ qf, const unsigned short* __restrict__ kf,
    const unsigned short* __restrict__ vt,
    const f32x4* __restrict__ ca4, const float* __restrict__ maskf,
    const float* __restrict__ cb, const float* __restrict__ fr,
    float* __restrict__ fa)
{
    __shared__ __align__(16) char smem[73728];
    const int tid = threadIdx.x;
    const int w = tid >> 6, lane = tid & 63;
    const int cL = lane & 15, gL = lane >> 4;
    const int qbase = blockIdx.x * 32;
    const int h = blockIdx.y;

    char* KsW  = smem + w*8192;              // [32][256B] XOR-swizzled
    char* AshW = KsW;                        // ALIAS: P buffer reuses own K tile

    bf16x8 qfrag[2][4];
    #pragma unroll
    for (int mt = 0; mt < 2; mt++)
        #pragma unroll
        for (int ks = 0; ks < 4; ks++)
            qfrag[mt][ks] = *(const bf16x8*)(qf + (size_t)(qbase + mt*16 + cL)*H_
                                             + h*HD_ + ks*32 + gL*8);
    float mq[2][4];
    #pragma unroll
    for (int mt = 0; mt < 2; mt++)
        #pragma unroll
        for (int j = 0; j < 4; j++)
            mq[mt][j] = (maskf[qbase + mt*16 + gL*4 + j] > 0.f) ? 1.f : 0.f;

    f32x4 O[2][8] = {};
    float den[2][4] = {}, axv[2][4] = {}, ayv[2][4] = {}, azv[2][4] = {};

    const unsigned short* kbase = kf + h*HD_;
    const unsigned short* vbase = vt + (size_t)h*HD_*R_;

    for (int kt = w; kt < 64; kt += 8) {
        const int kb = kt * 32;
        u32x4 tK[8];
        #pragma unroll
        for (int j = 0; j < 8; j++) {
            int flat = j*64 + lane;
            tK[j] = *(const u32x4*)(kbase + (size_t)(kb + (flat>>4))*H_ + (flat&15)*8);
        }
        bf16x8 vreg[8];
        #pragma unroll
        for (int dt = 0; dt < 8; dt++)
            vreg[dt] = *(const bf16x8*)(vbase + (size_t)(dt*16 + cL)*R_ + kb + gL*8);
        f32x4 cav[2];
        #pragma unroll
        for (int nt = 0; nt < 2; nt++)
            cav[nt] = ca4[kb + nt*16 + cL];
        #pragma unroll
        for (int j = 0; j < 8; j++) {
            int flat = j*64 + lane;
            int row = flat>>4, c = flat&15;
            *(u32x4*)(KsW + row*256 + ((c*16) ^ ((row&7)<<4))) = tK[j];
        }
        f32x4 sacc[2][2] = {};
        #pragma unroll
        for (int nt = 0; nt < 2; nt++) {
            int n = nt*16 + cL;
            int rs = (n&7)<<4;
            bf16x8 k0 = *(const bf16x8*)(KsW + n*256 + (((0*4+gL)*16) ^ rs));
            bf16x8 k1 = *(const bf16x8*)(KsW + n*256 + (((1*4+gL)*16) ^ rs));
            bf16x8 k2 = *(const bf16x8*)(KsW + n*256 + (((2*4+gL)*16) ^ rs));
            bf16x8 k3 = *(const bf16x8*)(KsW + n*256 + (((3*4+gL)*16) ^ rs));
            #pragma unroll
            for (int mt = 0; mt < 2; mt++) {
                sacc[mt][nt] = __builtin_amdgcn_mfma_f32_16x16x32_bf16(qfrag[mt][0], k0, sacc[mt][nt], 0,0,0);
                sacc[mt][nt] = __builtin_amdgcn_mfma_f32_16x16x32_bf16(qfrag[mt][1], k1, sacc[mt][nt], 0,0,0);
                sacc[mt][nt] = __builtin_amdgcn_mfma_f32_16x16x32_bf16(qfrag[mt][2], k2, sacc[mt][nt], 0,0,0);
                sacc[mt][nt] = __builtin_amdgcn_mfma_f32_16x16x32_bf16(qfrag[mt][3], k3, sacc[mt][nt], 0,0,0);
            }
        }
        unsigned short* arow = (unsigned short*)AshW;
        #pragma unroll
        for (int nt = 0; nt < 2; nt++) {
            #pragma unroll
            for (int mt = 0; mt < 2; mt++) {
                f32x4 s4 = sacc[mt][nt];
                float av[4];
                #pragma unroll
                for (int j = 0; j < 4; j++) {
                    float a = __expf(fminf(s4[j], 75.f)) * cav[nt][3] * mq[mt][j];
                    if (!(a < 3.0e38f)) a = 0.f;
                    av[j] = a;
                    den[mt][j] += a;
                    axv[mt][j] += a * cav[nt][0];
                    ayv[mt][j] += a * cav[nt][1];
                    azv[mt][j] += a * cav[nt][2];
                }
                unsigned int p01, p23;
                asm("v_cvt_pk_bf16_f32 %0, %1, %2" : "=v"(p01) : "v"(av[0]), "v"(av[1]));
                asm("v_cvt_pk_bf16_f32 %0, %1, %2" : "=v"(p23) : "v"(av[2]), "v"(av[3]));
                int qr = mt*16 + gL*4;
                int col = nt*16 + cL;
                arow[(qr+0)*40 + col] = (unsigned short)p01;
                arow[(qr+1)*40 + col] = (unsigned short)(p01 >> 16);
                arow[(qr+2)*40 + col] = (unsigned short)p23;
                arow[(qr+3)*40 + col] = (unsigned short)(p23 >> 16);
            }
        }
        bf16x8 pa0 = *(const bf16x8*)(AshW + ((size_t)(cL)*40      + gL*8)*2);
        bf16x8 pa1 = *(const bf16x8*)(AshW + ((size_t)(16 + cL)*40 + gL*8)*2);
        #pragma unroll
        for (int dt = 0; dt < 8; dt++) {
            O[0][dt] = __builtin_amdgcn_mfma_f32_16x16x32_bf16(pa0, vreg[dt], O[0][dt], 0,0,0);
            O[1][dt] = __builtin_amdgcn_mfma_f32_16x16x32_bf16(pa1, vreg[dt], O[1][dt], 0,0,0);
        }
    }

    __syncthreads();
    float* Ored = (float*)smem;            // [8][32][68]
    float* dred = (float*)(smem + 69632);  // [8][32][4]
    #pragma unroll
    for (int mt = 0; mt < 2; mt++)
        #pragma unroll
        for (int j = 0; j < 4; j++) {
            float d0 = den[mt][j], x0 = axv[mt][j], y0 = ayv[mt][j], z0 = azv[mt][j];
            #pragma unroll
            for (int off = 8; off >= 1; off >>= 1) {
                d0 += __shfl_xor(d0, off); x0 += __shfl_xor(x0, off);
                y0 += __shfl_xor(y0, off); z0 += __shfl_xor(z0, off);
            }
            if (cL == 0) {
                f32x4 v; v[0]=d0; v[1]=x0; v[2]=y0; v[3]=z0;
                *(f32x4*)&dred[w*128 + (mt*16 + gL*4 + j)*4] = v;
            }
        }
    #pragma unroll
    for (int mt = 0; mt < 2; mt++)
        #pragma unroll
        for (int dtl = 0; dtl < 4; dtl++) {
            f32x4 o4 = O[mt][dtl];
            #pragma unroll
            for (int j = 0; j < 4; j++)
                Ored[w*2176 + (mt*16 + gL*4 + j)*68 + dtl*16 + cL] = o4[j];
        }
    __syncthreads();
    {
        int q = tid >> 4, c4 = (tid & 15) * 4;
        float dn = 0.f;
        #pragma unroll
        for (int ww = 0; ww < 8; ww++) dn += dred[ww*128 + q*4];
        float inv = (dn > 0.f) ? 1.f/dn : 0.f;
        f32x4 s = *(const f32x4*)&Ored[q*68 + c4];
        #pragma unroll
        for (int ww = 1; ww < 8; ww++)
            s += *(const f32x4*)&Ored[ww*2176 + q*68 + c4];
        *(f32x4*)&fa[(size_t)(qbase+q)*FA_LD + h*HD_ + c4] = s * inv;
    }
    if (tid < 32) {
        float dn=0.f, ax=0.f, ay=0.f, az=0.f;
        #pragma unroll
        for (int ww = 0; ww < 8; ww++) {
            const float* dp = &dred[ww*128 + tid*4];
            dn += dp[0]; ax += dp[1]; ay += dp[2]; az += dp[3];
        }
        float inv = (dn > 0.f) ? 1.f/dn : 0.f;
        float live = (dn > 0.f) ? 1.f : 0.f;
        int qg = qbase + tid;
        float b0 = cb[qg*3+0]*live - ax*inv;
        float b1 = cb[qg*3+1]*live - ay*inv;
        float b2 = cb[qg*3+2]*live - az*inv;
        float dist = sqrtf(b0*b0 + b1*b1 + b2*b2);
        const float* F = fr + (size_t)qg*9;
        float p0 = F[0]*b0 + F[1]*b1 + F[2]*b2;
        float p1 = F[3]*b0 + F[4]*b1 + F[5]*b2;
        float p2 = F[6]*b0 + F[7]*b1 + F[8]*b2;
        float pn = sqrtf(p0*p0 + p1*p1 + p2*p2) + 1e-10f;
        size_t rb = (size_t)qg * FA_LD;
        fa[rb + 512 + h*3 + 0] = p0;
        fa[rb + 512 + h*3 + 1] = p1;
        fa[rb + 512 + h*3 + 2] = p2;
        fa[rb + 524 + h]       = dist;
        fa[rb + 528 + h*3 + 0] = p0/pn;
        fa[rb + 528 + h*3 + 1] = p1/pn;
        fa[rb + 528 + h*3 + 2] = p2/pn;
        if (h == 0) { fa[rb+540]=0.f; fa[rb+541]=0.f; fa[rb+542]=0.f; fa[rb+543]=0.f; }
    }
    __syncthreads();
    #pragma unroll
    for (int mt = 0; mt < 2; mt++)
        #pragma unroll
        for (int dtl = 0; dtl < 4; dtl++) {
            f32x4 o4 = O[mt][4 + dtl];
            #pragma unroll
            for (int j = 0; j < 4; j++)
                Ored[w*2176 + (mt*16 + gL*4 + j)*68 + dtl*16 + cL] = o4[j];
        }
    __syncthreads();
    {
        int q = tid >> 4, c4 = (tid & 15) * 4;
        float dn = 0.f;
        #pragma unroll
        for (int ww = 0; ww < 8; ww++) dn += dred[ww*128 + q*4];
        float inv = (dn > 0.f) ? 1.f/dn : 0.f;
        f32x4 s = *(const f32x4*)&Ored[q*68 + c4];
        #pragma unroll
        for (int ww = 1; ww < 8; ww++)
            s += *(const f32x4*)&Ored[ww*2176 + q*68 + c4];
        *(f32x4*)&fa[(size_t)(qbase+q)*FA_LD + h*HD_ + 64 + c4] = s * inv;
    }
}

// ---------------------------------------------------------------- relu+LN1+mask+res+LN2 (R17 verbatim)
__global__ __launch_bounds__(256) void final_ln(
    const float* __restrict__ Y, const void* __restrict__ nf,
    const int* __restrict__ cai, const float* __restrict__ maskf,
    const void* __restrict__ g1, const void* __restrict__ b1,
    const void* __restrict__ g2, const void* __restrict__ b2,
    void* __restrict__ out, const int* __restrict__ flag)
{
    const int tid = threadIdx.x, lane = tid & 63, wave = tid >> 6;
    const int r = blockIdx.x * 4 + wave;
    bool f32 = *flag != 0;
    const float mk = maskf[r];
    const size_t xrow = (size_t)cai[r] * H_;
    float y[8], s1 = 0.f, s2 = 0.f;
    #pragma unroll
    for (int i = 0; i < 8; i++) {
        int c = lane + i*64;
        float v = fmaxf(Y[(size_t)r*H_ + c], 0.f);
        y[i] = v; s1 += v; s2 += v*v;
    }
    #pragma unroll
    for (int off = 32; off; off >>= 1) { s1 += __shfl_xor(s1, off); s2 += __shfl_xor(s2, off); }
    float mu = s1 * (1.f/H_);
    float var = s2 * (1.f/H_) - mu*mu;
    float rstd = rsqrtf(fmaxf(var, 0.f) + 1e-5f);
    float t[8], u1 = 0.f, u2 = 0.f;
    #pragma unroll
    for (int i = 0; i < 8; i++) {
        int c = lane + i*64;
        float hh = (y[i]-mu)*rstd*loadf(g1, c, f32) + loadf(b1, c, f32);
        hh *= mk;
        float tv = loadf(nf, xrow + c, f32) + hh;
        t[i] = tv; u1 += tv; u2 += tv*tv;
    }
    #pragma unroll
    for (int off = 32; off; off >>= 1) { u1 += __shfl_xor(u1, off); u2 += __shfl_xor(u2, off); }
    float mu2 = u1 * (1.f/H_);
    float var2 = u2 * (1.f/H_) - mu2*mu2;
    float rstd2 = rsqrtf(fmaxf(var2, 0.f) + 1e-5f);
    #pragma unroll
    for (int i = 0; i < 8; i++) {
        int c = lane + i*64;
        float ov = (t[i]-mu2)*rstd2*loadf(g2, c, f32) + loadf(b2, c, f32);
        if (f32) ((float*)out)[(size_t)r*H_ + c] = ov;
        else ((unsigned short*)out)[(size_t)r*H_ + c] = f2bf(ov);
    }
}

// ---------------------------------------------------------------- launch
extern "C" void kernel_launch(void* const* d_in, const int* in_sizes, int n_in,
                              void* d_out, int out_size, void* d_ws, size_t ws_size,
                              hipStream_t stream)
{
    static const int expected[16] = {
        8388608, 49152, 262144, 512, 262144, 512, 262144, 512,
        276480, 512, 512, 512, 512, 512, 16384, 16384
    };
    if (n_in != 16) {
        diag<<<dim3(1), dim3(64), 0, stream>>>((unsigned short*)d_out, 1000.f + n_in);
        return;
    }
    for (int i = 0; i < 16; i++) {
        if (in_sizes[i] != expected[i]) {
            diag<<<dim3(1), dim3(64), 0, stream>>>((unsigned short*)d_out, 2000.f + 10.f*i);
            return;
        }
    }
    const size_t need = 16056320;
    if (ws_size < need) {
        diag<<<dim3(1), dim3(64), 0, stream>>>((unsigned short*)d_out, 3000.f);
        return;
    }

    const void* nf  = d_in[0];
    const void* pos = d_in[1];
    const void* Wq  = d_in[2];  const void* bq = d_in[3];
    const void* Wk  = d_in[4];  const void* bk = d_in[5];
    const void* Wv  = d_in[6];  const void* bv = d_in[7];
    const void* Wo  = d_in[8];  const void* bo = d_in[9];
    const void* g1  = d_in[10]; const void* b1 = d_in[11];
    const void* g2  = d_in[12]; const void* b2 = d_in[13];
    const int* atype = (const int*)d_in[14];

    char* ws = (char*)d_ws;
    int*   flag  = (int*)  (ws + 0);
    int*   cai   = (int*)  (ws + 1024);
    float* ca    = (float*)(ws + 9216);
    float* cb    = (float*)(ws + 33792);
    float* fr    = (float*)(ws + 58368);
    float* maskf = (float*)(ws + 132096);
    f32x4* ca4   = (f32x4*)(ws + 140288);                   // [2048] (ca.xyz, mask)
    unsigned short* qf = (unsigned short*)(ws + 1048576);
    unsigned short* kf = (unsigned short*)(ws + 3145728);
    unsigned short* vt = (unsigned short*)(ws + 5242880);   // [512][2048] bf16
    unsigned short* xg_hi = (unsigned short*)(ws + 7340032);
    unsigned short* xg_lo = (unsigned short*)(ws + 9437184);
    float* fa = (float*)(ws + 7340032);                     // [2048][544] f32 (aliases xg)
    unsigned short* wqt_hi = (unsigned short*)(ws + 11796480);
    unsigned short* wqt_lo = (unsigned short*)(ws + 13369344);
    unsigned short* wot_hi = (unsigned short*)(ws + 14942208);
    unsigned short* wot_lo = (unsigned short*)(ws + 15499264);
    float* Y  = (float*)qf;   // aliases qf+kf (4 MB) — both dead after attn

    prep_all<<<dim3(2072), dim3(256), 0, stream>>>(nf, pos, atype, Wq, Wk, Wv, Wo,
                                                   flag, cai, ca, cb, fr, maskf, ca4,
                                                   xg_hi, xg_lo, wqt_hi, wqt_lo,
                                                   wot_hi, wot_lo);
    qkv_mfma<<<dim3(32, 24), dim3(256), 0, stream>>>(xg_hi, xg_lo, wqt_hi, wqt_lo,
                                                     bq, bk, bv, qf, kf, vt, flag);
    attn_mfma3<<<dim3(R_/32, HEADS_), dim3(512), 0, stream>>>(qf, kf, vt, ca4, maskf,
                                                              cb, fr, fa);
    wo_mfma<<<dim3(32, 8), dim3(256), 0, stream>>>(fa, wot_hi, wot_lo, bo, Y, flag);
    final_ln<<<dim3(512), dim3(256), 0, stream>>>(Y, nf, cai, maskf, g1, b1, g2, b2,
                                                  d_out, flag);
}